// Round 13
// baseline (826.454 us; speedup 1.0000x reference)
//
#include <hip/hip_runtime.h>
#include <math.h>

#define TB 256
#define SCAN_TOT 106250
#define SCAN_NB  104

typedef __bf16 bf16x8 __attribute__((ext_vector_type(8)));
typedef float f32x4 __attribute__((ext_vector_type(4)));
typedef float f32x2 __attribute__((ext_vector_type(2)));

static __device__ __forceinline__ int gtid() { return blockIdx.x * blockDim.x + threadIdx.x; }

static __device__ __forceinline__ void fma4(float4& a, float s, const float4 b) {
  a.x = fmaf(s, b.x, a.x); a.y = fmaf(s, b.y, a.y);
  a.z = fmaf(s, b.z, a.z); a.w = fmaf(s, b.w, a.w);
}

static __device__ __forceinline__ float bfus(unsigned short u) {
  union { unsigned u; float f; } c; c.u = ((unsigned)u) << 16; return c.f;
}
static __device__ __forceinline__ unsigned pk2(float a, float b) {
  union { unsigned u; __bf16 h[2]; } c;
  c.h[0] = (__bf16)a; c.h[1] = (__bf16)b;
  return c.u;
}
static __device__ __forceinline__ unsigned short us1(float a) {
  union { unsigned short u; __bf16 h; } c; c.h = (__bf16)a; return c.u;
}
static __device__ __forceinline__ f32x2 unpk(unsigned u) {
  union { unsigned u; float f; } lo, hi;
  lo.u = u << 16; hi.u = u & 0xffff0000u;
  f32x2 r; r.x = lo.f; r.y = hi.f; return r;
}

__global__ void fill_kernel(float* __restrict__ p, int n, float v) {
  int i = gtid(); if (i < n) p[i] = v;
}

__global__ void zero_int_kernel(int* __restrict__ p, int n) {
  int i = gtid(); if (i < n) p[i] = 0;
}

struct SegD {
  const int* rows[8];
  const int* cols[8];
  const float* vals[8];  // null => edge seg (compute sym-norm weight)
  int start[8];
  int degb[8];
};

__global__ void count_all_kernel(SegD sg, int total, int* __restrict__ deg) {
  int t = gtid(); if (t >= total) return;
  int seg = 0;
  #pragma unroll
  for (int q = 1; q < 8; ++q) seg += (t >= sg.start[q]);
  int i = t - sg.start[seg];
  atomicAdd(&deg[sg.degb[seg] + sg.rows[seg][i]], 1);
}

// fused (col, weight-bits) CSR arena
__global__ void fill_all_kernel(SegD sg, int total, const int* __restrict__ deg,
                                const int* __restrict__ offs, int* __restrict__ cursor,
                                int2* __restrict__ cwc) {
  int t = gtid(); if (t >= total) return;
  int seg = 0;
  #pragma unroll
  for (int q = 1; q < 8; ++q) seg += (t >= sg.start[q]);
  int i = t - sg.start[seg];
  int db = sg.degb[seg];
  int r = sg.rows[seg][i];
  int c = sg.cols[seg][i];
  int p = atomicAdd(&cursor[db + r], 1);
  int idx = offs[db + r] + p;
  float w;
  if (sg.vals[seg]) {
    w = sg.vals[seg][i];
  } else {
    int dc = deg[db + c];
    w = rsqrtf((float)deg[db + r]) * (dc > 0 ? rsqrtf((float)dc) : 0.f);
  }
  int2 o; o.x = c; o.y = __float_as_int(w);
  cwc[idx] = o;
}

// ---- 3-phase global exclusive scan over deg ----
__global__ void scan_phase1(const int* __restrict__ in, int* __restrict__ bsum) {
  __shared__ int wsum[4];
  int blk = blockIdx.x, t = threadIdx.x;
  int base = blk * 1024 + t * 4;
  int s = 0;
  #pragma unroll
  for (int q = 0; q < 4; ++q) { int i = base + q; if (i < SCAN_TOT) s += in[i]; }
  #pragma unroll
  for (int o = 32; o > 0; o >>= 1) s += __shfl_xor(s, o, 64);
  int lane = t & 63, wid = t >> 6;
  if (lane == 0) wsum[wid] = s;
  __syncthreads();
  if (t == 0) bsum[blk] = wsum[0] + wsum[1] + wsum[2] + wsum[3];
}

__global__ void scan_phase2(int* __restrict__ bsum, int* __restrict__ offs_end) {
  int t = threadIdx.x;  // 128
  int v = (t < SCAN_NB) ? bsum[t] : 0;
  int lane = t & 63, wid = t >> 6;
  int p = v;
  #pragma unroll
  for (int o = 1; o < 64; o <<= 1) { int u = __shfl_up(p, o, 64); if (lane >= o) p += u; }
  __shared__ int w0tot;
  if (wid == 0 && lane == 63) w0tot = p;
  __syncthreads();
  int incl = p + (wid ? w0tot : 0);
  if (t < SCAN_NB) bsum[t] = incl - v;
  if (t == 127) offs_end[0] = incl;
}

__global__ void scan_phase3(const int* __restrict__ in, const int* __restrict__ bbase,
                            int* __restrict__ offs, int* __restrict__ cursor) {
  __shared__ int wsum[4];
  int blk = blockIdx.x, t = threadIdx.x;
  int base = blk * 1024 + t * 4;
  int v[4]; int s = 0;
  #pragma unroll
  for (int q = 0; q < 4; ++q) { int i = base + q; v[q] = (i < SCAN_TOT) ? in[i] : 0; s += v[q]; }
  int lane = t & 63, wid = t >> 6;
  int p = s;
  #pragma unroll
  for (int o = 1; o < 64; o <<= 1) { int u = __shfl_up(p, o, 64); if (lane >= o) p += u; }
  if (lane == 63) wsum[wid] = p;
  __syncthreads();
  int woff = 0;
  #pragma unroll
  for (int q = 0; q < 4; ++q) woff += (q < wid) ? wsum[q] : 0;
  int ex = bbase[blk] + woff + p - s;
  #pragma unroll
  for (int q = 0; q < 4; ++q) {
    int i = base + q;
    if (i < SCAN_TOT) { offs[i] = ex; cursor[i] = 0; ex += v[q]; }
  }
}

// W [6][32k][32col] f32 -> Wt bf16 [6][32col][32k] (packed pairs of k)
__global__ void wconv_kernel(const float* __restrict__ W, unsigned* __restrict__ Wt) {
  int p = gtid();
  if (p >= 6 * 32 * 16) return;
  int kk2 = p & 15;
  int col = (p >> 4) & 31;
  int kidx = p >> 9;
  float v0 = W[kidx * 1024 + (2 * kk2) * 32 + col];
  float v1 = W[kidx * 1024 + (2 * kk2 + 1) * 32 + col];
  Wt[(kidx * 32 + col) * 16 + kk2] = pk2(v0, v1);
}

// ---- fp32 pool (upper levels) ----
__global__ void pool_kernel(const float4* __restrict__ x, const int* __restrict__ offs,
                            const int2* __restrict__ cwc,
                            float4* __restrict__ out, int n, int xs4, int xoff4,
                            int os4, int osh) {
  int t = gtid();
  if (t >= n * os4) return;
  int v = t >> osh, j = t & (os4 - 1);
  int s = offs[v], e = offs[v + 1];
  float4 a = {0.f, 0.f, 0.f, 0.f};
  for (int i = s; i < e; ++i) {
    int2 cw = cwc[i];
    fma4(a, __int_as_float(cw.y), x[(long long)cw.x * xs4 + xoff4 + j]);
  }
  out[t] = a;
}

// ---- Fused pool + Clenshaw step k=5 (mode 0) ----
// R rows (batch slice) per vertex; 16/R vertices per wave. Lane's A-row c15
// maps to vertex va = vbase + c15/R, row ra = c15%R; gather uses va's pool
// CSR (per-lane bounds). Output D rows 4g..4g+3 -> vertex vl = vbase+4g/R.
// X/b5 half layouts: [v][R][32]; state lane-blocked uint4 @ v*4R + gl*16 + c15.
// SRC 0: x = fp32 [u][16][32] (browoff=0); SRC 1: x = bf16 [u][16][32], rows browoff+ra
template<int SRC, int R>
__global__ void __launch_bounds__(256)
pool_mfma_kernel(const void* __restrict__ xsrc, const int* __restrict__ offs,
                 const int2* __restrict__ cwc,
                 uint4* __restrict__ Xout, uint4* __restrict__ b5out,
                 const uint4* __restrict__ Wtk5, int browoff, int n) {
  constexpr int VW = 16 / R;
  constexpr int U4V = 4 * R;
  int lane = threadIdx.x & 63;
  int vbase = ((blockIdx.x << 2) | (threadIdx.x >> 6)) * VW;
  if (vbase >= n) return;
  int g = lane >> 4, c15 = lane & 15;
  int va = vbase + c15 / R;
  int ra = c15 % R;
  int srow = browoff + ra;
  int s = offs[va], e = offs[va + 1];
  int deg = e - s;
  float a[8];
  #pragma unroll
  for (int q = 0; q < 8; ++q) a[q] = 0.f;

  if (deg > 0) {
    if (SRC == 0) {
      const float4* x = (const float4*)xsrc;
      float4 x0[4], x1[4]; float ww[4];
      #pragma unroll
      for (int p = 0; p < 4; ++p) {
        int idx = s + (p < deg ? p : 0);
        int2 cw = cwc[idx];
        ww[p] = (p < deg) ? __int_as_float(cw.y) : 0.f;
        const float4* xr = x + (long long)cw.x * 128 + srow * 8 + g * 2;
        x0[p] = xr[0]; x1[p] = xr[1];
      }
      #pragma unroll
      for (int p = 0; p < 4; ++p) {
        float w = ww[p];
        a[0] = fmaf(w, x0[p].x, a[0]); a[1] = fmaf(w, x0[p].y, a[1]);
        a[2] = fmaf(w, x0[p].z, a[2]); a[3] = fmaf(w, x0[p].w, a[3]);
        a[4] = fmaf(w, x1[p].x, a[4]); a[5] = fmaf(w, x1[p].y, a[5]);
        a[6] = fmaf(w, x1[p].z, a[6]); a[7] = fmaf(w, x1[p].w, a[7]);
      }
      for (int i = s + 4; i < e; ++i) {
        int2 cw = cwc[i];
        float w = __int_as_float(cw.y);
        const float4* xr = x + (long long)cw.x * 128 + srow * 8 + g * 2;
        float4 y0 = xr[0], y1 = xr[1];
        a[0] = fmaf(w, y0.x, a[0]); a[1] = fmaf(w, y0.y, a[1]);
        a[2] = fmaf(w, y0.z, a[2]); a[3] = fmaf(w, y0.w, a[3]);
        a[4] = fmaf(w, y1.x, a[4]); a[5] = fmaf(w, y1.y, a[5]);
        a[6] = fmaf(w, y1.z, a[6]); a[7] = fmaf(w, y1.w, a[7]);
      }
    } else {
      const uint4* x = (const uint4*)xsrc;
      uint4 bv[4]; float ww[4];
      #pragma unroll
      for (int p = 0; p < 4; ++p) {
        int idx = s + (p < deg ? p : 0);
        int2 cw = cwc[idx];
        ww[p] = (p < deg) ? __int_as_float(cw.y) : 0.f;
        bv[p] = x[(long long)cw.x * 64 + srow * 4 + g];
      }
      #pragma unroll
      for (int p = 0; p < 4; ++p) {
        f32x2 w2 = {ww[p], ww[p]};
        f32x2 r0 = __builtin_elementwise_fma(w2, unpk(bv[p].x), f32x2{a[0], a[1]});
        f32x2 r1 = __builtin_elementwise_fma(w2, unpk(bv[p].y), f32x2{a[2], a[3]});
        f32x2 r2 = __builtin_elementwise_fma(w2, unpk(bv[p].z), f32x2{a[4], a[5]});
        f32x2 r3 = __builtin_elementwise_fma(w2, unpk(bv[p].w), f32x2{a[6], a[7]});
        a[0] = r0.x; a[1] = r0.y; a[2] = r1.x; a[3] = r1.y;
        a[4] = r2.x; a[5] = r2.y; a[6] = r3.x; a[7] = r3.y;
      }
      for (int i = s + 4; i < e; ++i) {
        int2 cw = cwc[i];
        float w = __int_as_float(cw.y);
        f32x2 w2 = {w, w};
        uint4 xv = x[(long long)cw.x * 64 + srow * 4 + g];
        f32x2 r0 = __builtin_elementwise_fma(w2, unpk(xv.x), f32x2{a[0], a[1]});
        f32x2 r1 = __builtin_elementwise_fma(w2, unpk(xv.y), f32x2{a[2], a[3]});
        f32x2 r2 = __builtin_elementwise_fma(w2, unpk(xv.z), f32x2{a[4], a[5]});
        f32x2 r3 = __builtin_elementwise_fma(w2, unpk(xv.w), f32x2{a[6], a[7]});
        a[0] = r0.x; a[1] = r0.y; a[2] = r1.x; a[3] = r1.y;
        a[4] = r2.x; a[5] = r2.y; a[6] = r3.x; a[7] = r3.y;
      }
    }
  }
  union { uint4 u; bf16x8 b; } Au;
  Au.u.x = pk2(a[0], a[1]); Au.u.y = pk2(a[2], a[3]);
  Au.u.z = pk2(a[4], a[5]); Au.u.w = pk2(a[6], a[7]);
  Xout[(long long)va * U4V + ra * 4 + g] = Au.u;

  union { uint4 u; bf16x8 b; } B0u, B1u;
  B0u.u = Wtk5[c15 * 4 + g];
  B1u.u = Wtk5[(16 + c15) * 4 + g];
  f32x4 z = {0.f, 0.f, 0.f, 0.f};
  f32x4 m0 = __builtin_amdgcn_mfma_f32_16x16x32_bf16(Au.b, B0u.b, z, 0, 0, 0);
  f32x4 m1 = __builtin_amdgcn_mfma_f32_16x16x32_bf16(Au.b, B1u.b, z, 0, 0, 0);
  int vl = vbase + (4 * g) / R;
  int gl = g % (R / 4);
  uint4 o;
  o.x = pk2(m0[0], m1[0]); o.y = pk2(m0[1], m1[1]);
  o.z = pk2(m0[2], m1[2]); o.w = pk2(m0[3], m1[3]);
  b5out[(long long)vl * U4V + gl * 16 + c15] = o;
}

// ---- fp32 channel-split Clenshaw step (upper levels j=0,1) ----
template<int CIN, int COUT>
__global__ void cheb_step_kernel(const float* __restrict__ X,
                                 const float* __restrict__ b1,
                                 float* __restrict__ b2o,
                                 const float* __restrict__ Wk,
                                 const float* __restrict__ bias,
                                 const int* __restrict__ offs,
                                 const int2* __restrict__ cwc,
                                 int n, int LB, int mode) {
  constexpr int CS = COUT / 8;
  constexpr int LCS = (CS == 8) ? 3 : 2;
  constexpr int W4 = COUT / 4;
  __shared__ float sW[CIN * COUT];
  for (int i = threadIdx.x; i < CIN * COUT; i += blockDim.x) sW[i] = Wk[i];
  __syncthreads();
  int t = gtid();
  int BI = 1 << LB;
  if (t >= n * BI * CS) return;
  int cs = t & (CS - 1);
  int r = t >> LCS;
  int v = r >> LB;
  int bi = r & (BI - 1);
  float4 a0 = {0.f, 0.f, 0.f, 0.f}, a1 = {0.f, 0.f, 0.f, 0.f};
  const float4* Xr = (const float4*)(X + (long long)r * CIN);
  const float4* wbase = ((const float4*)sW) + cs * 2;
  #pragma unroll
  for (int c4 = 0; c4 < CIN / 4; ++c4) {
    float4 xv = Xr[c4];
    const float4* w = wbase + (c4 * 4) * W4;
    fma4(a0, xv.x, w[0]); fma4(a1, xv.x, w[1]); w += W4;
    fma4(a0, xv.y, w[0]); fma4(a1, xv.y, w[1]); w += W4;
    fma4(a0, xv.z, w[0]); fma4(a1, xv.z, w[1]); w += W4;
    fma4(a0, xv.w, w[0]); fma4(a1, xv.w, w[1]);
  }
  if (mode >= 1) {
    float sc = (mode == 3) ? 1.f : 2.f;
    int s = offs[v], e = offs[v + 1];
    const float4* b14 = (const float4*)b1;
    for (int i = s; i < e; ++i) {
      int2 cw = cwc[i];
      float w = __int_as_float(cw.y) * sc;
      long long rb = (long long)((cw.x << LB) | bi) * W4 + cs * 2;
      fma4(a0, w, b14[rb]); fma4(a1, w, b14[rb + 1]);
    }
  }
  float4* Or = ((float4*)b2o) + (long long)r * W4 + cs * 2;
  if (mode >= 2) {
    float4 p0 = Or[0], p1 = Or[1];
    a0.x -= p0.x; a0.y -= p0.y; a0.z -= p0.z; a0.w -= p0.w;
    a1.x -= p1.x; a1.y -= p1.y; a1.z -= p1.z; a1.w -= p1.w;
  }
  if (mode == 3) {
    const float* bs = bias + cs * 8;
    a0.x += bs[0]; a0.y += bs[1]; a0.z += bs[2]; a0.w += bs[3];
    a1.x += bs[4]; a1.y += bs[5]; a1.z += bs[6]; a1.w += bs[7];
    a0.x = a0.x > 0.f ? a0.x : expm1f(a0.x);
    a0.y = a0.y > 0.f ? a0.y : expm1f(a0.y);
    a0.z = a0.z > 0.f ? a0.z : expm1f(a0.z);
    a0.w = a0.w > 0.f ? a0.w : expm1f(a0.w);
    a1.x = a1.x > 0.f ? a1.x : expm1f(a1.x);
    a1.y = a1.y > 0.f ? a1.y : expm1f(a1.y);
    a1.z = a1.z > 0.f ? a1.z : expm1f(a1.z);
    a1.w = a1.w > 0.f ? a1.w : expm1f(a1.w);
  }
  Or[0] = a0; Or[1] = a1;
}

// ---- MFMA Clenshaw step, R rows per vertex (16: full batch; 8: half batch) ----
// 16/R vertices per wave. X [v][R][32] bf16; state lane-blocked uint4 @
// v*4R + gl*16 + c15 (gl = row-group within vertex). 8-deep prefetch gather
// with per-lane CSR bounds. mode 3 writes LINEAR bf16 [v][R][32] (in-place ok).
template<int R>
__global__ void __launch_bounds__(256)
cheb_mfma32_kernel(const uint4* __restrict__ X,
                   const uint4* __restrict__ b1,
                   uint4* __restrict__ b2o,
                   const uint4* __restrict__ Wtk,
                   const float* __restrict__ bias,
                   const int* __restrict__ offs,
                   const int2* __restrict__ cwc,
                   int n, int mode) {
  constexpr int VW = 16 / R;
  constexpr int U4V = 4 * R;
  int lane = threadIdx.x & 63;
  int vbase = ((blockIdx.x << 2) | (threadIdx.x >> 6)) * VW;
  if (vbase >= n) return;
  int g = lane >> 4;
  int c15 = lane & 15;
  int va = vbase + c15 / R;
  int ra = c15 % R;

  union { uint4 u; bf16x8 b; } Au, B0u, B1u;
  Au.u = X[(long long)va * U4V + ra * 4 + g];
  B0u.u = Wtk[c15 * 4 + g];
  B1u.u = Wtk[(16 + c15) * 4 + g];

  f32x4 z = {0.f, 0.f, 0.f, 0.f};
  f32x4 m0 = __builtin_amdgcn_mfma_f32_16x16x32_bf16(Au.b, B0u.b, z, 0, 0, 0);
  f32x4 m1 = __builtin_amdgcn_mfma_f32_16x16x32_bf16(Au.b, B1u.b, z, 0, 0, 0);
  f32x2 acc[4];
  #pragma unroll
  for (int q = 0; q < 4; ++q) { acc[q].x = m0[q]; acc[q].y = m1[q]; }

  int vl = vbase + (4 * g) / R;
  int gl = g % (R / 4);
  long long own = (long long)vl * U4V + gl * 16 + c15;
  if (mode >= 1) {
    float sc = (mode == 3) ? 1.f : 2.f;
    int s = offs[vl], e = offs[vl + 1];
    int deg = e - s;
    if (deg > 0) {
      uint4 bv[8]; float ww[8];
      #pragma unroll
      for (int p = 0; p < 8; ++p) {
        int idx = s + (p < deg ? p : 0);
        int2 cw = cwc[idx];
        ww[p] = (p < deg) ? __int_as_float(cw.y) * sc : 0.f;
        bv[p] = b1[(long long)cw.x * U4V + gl * 16 + c15];
      }
      #pragma unroll
      for (int p = 0; p < 8; ++p) {
        f32x2 w2 = {ww[p], ww[p]};
        acc[0] = __builtin_elementwise_fma(w2, unpk(bv[p].x), acc[0]);
        acc[1] = __builtin_elementwise_fma(w2, unpk(bv[p].y), acc[1]);
        acc[2] = __builtin_elementwise_fma(w2, unpk(bv[p].z), acc[2]);
        acc[3] = __builtin_elementwise_fma(w2, unpk(bv[p].w), acc[3]);
      }
      for (int i = s + 8; i < e; ++i) {
        int2 cw = cwc[i];
        float w = __int_as_float(cw.y) * sc;
        f32x2 w2 = {w, w};
        uint4 xv = b1[(long long)cw.x * U4V + gl * 16 + c15];
        acc[0] = __builtin_elementwise_fma(w2, unpk(xv.x), acc[0]);
        acc[1] = __builtin_elementwise_fma(w2, unpk(xv.y), acc[1]);
        acc[2] = __builtin_elementwise_fma(w2, unpk(xv.z), acc[2]);
        acc[3] = __builtin_elementwise_fma(w2, unpk(xv.w), acc[3]);
      }
    }
  }
  if (mode >= 2) {
    uint4 pv = b2o[own];
    acc[0] -= unpk(pv.x); acc[1] -= unpk(pv.y);
    acc[2] -= unpk(pv.z); acc[3] -= unpk(pv.w);
  }
  if (mode == 3) {
    float bs0 = bias[c15], bs1 = bias[16 + c15];
    unsigned short* o = (unsigned short*)b2o;
    long long lb = ((long long)vl * R + gl * 4) * 32;
    #pragma unroll
    for (int q = 0; q < 4; ++q) {
      float a = acc[q].x + bs0;
      float b = acc[q].y + bs1;
      a = a > 0.f ? a : expm1f(a);
      b = b > 0.f ? b : expm1f(b);
      o[lb + q * 32 + c15] = us1(a);
      o[lb + q * 32 + 16 + c15] = us1(b);
    }
  } else {
    uint4 o;
    o.x = pk2(acc[0].x, acc[0].y); o.y = pk2(acc[1].x, acc[1].y);
    o.z = pk2(acc[2].x, acc[2].y); o.w = pk2(acc[3].x, acc[3].y);
    b2o[own] = o;
  }
}

// c_all[k][r][3] (bf16) = X[r]·Wout[k], X linear bf16 [r][32]
__global__ void gemm_out_all_kernel(const uint4* __restrict__ X, const float* __restrict__ W,
                                    unsigned short* __restrict__ c_all, int nr) {
  __shared__ float sW[576];
  for (int i = threadIdx.x; i < 576; i += blockDim.x) sW[i] = W[i];
  __syncthreads();
  int r = gtid();
  if (r >= nr) return;
  const uint4* Xr = X + (long long)r * 4;
  float xa[32];
  #pragma unroll
  for (int q = 0; q < 4; ++q) {
    uint4 xv = Xr[q];
    f32x2 p0 = unpk(xv.x), p1 = unpk(xv.y), p2 = unpk(xv.z), p3 = unpk(xv.w);
    xa[q * 8 + 0] = p0.x; xa[q * 8 + 1] = p0.y;
    xa[q * 8 + 2] = p1.x; xa[q * 8 + 3] = p1.y;
    xa[q * 8 + 4] = p2.x; xa[q * 8 + 5] = p2.y;
    xa[q * 8 + 6] = p3.x; xa[q * 8 + 7] = p3.y;
  }
  float acc[18];
  #pragma unroll
  for (int i = 0; i < 18; ++i) acc[i] = 0.f;
  #pragma unroll
  for (int c = 0; c < 32; ++c) {
    float xc = xa[c];
    #pragma unroll
    for (int k = 0; k < 6; ++k) {
      acc[k * 3 + 0] = fmaf(xc, sW[k * 96 + c * 3 + 0], acc[k * 3 + 0]);
      acc[k * 3 + 1] = fmaf(xc, sW[k * 96 + c * 3 + 1], acc[k * 3 + 1]);
      acc[k * 3 + 2] = fmaf(xc, sW[k * 96 + c * 3 + 2], acc[k * 3 + 2]);
    }
  }
  #pragma unroll
  for (int k = 0; k < 6; ++k) {
    unsigned short* o = c_all + ((long long)k * nr + r) * 3;
    o[0] = us1(acc[k * 3 + 0]);
    o[1] = us1(acc[k * 3 + 1]);
    o[2] = us1(acc[k * 3 + 2]);
  }
}

// Clenshaw on tiny 3-ch buffers; r = v*(1<<lb)+bi; mode3 -> dout[((boff+bi)*n+v)*3]
__global__ void cheb_out_step_kernel(const unsigned short* __restrict__ c_all, int k,
                                     const float* __restrict__ b1,
                                     float* __restrict__ b2o,
                                     const float* __restrict__ bias,
                                     const int* __restrict__ offs,
                                     const int2* __restrict__ cwc,
                                     int n, int lb, int boff,
                                     float* __restrict__ dout, int mode) {
  int BI = 1 << lb;
  int r = gtid();
  if (r >= n * BI) return;
  int v = r >> lb, bi = r & (BI - 1);
  int nr = n << lb;
  const unsigned short* cr = c_all + ((long long)k * nr + r) * 3;
  float a0 = bfus(cr[0]), a1 = bfus(cr[1]), a2 = bfus(cr[2]);
  if (mode >= 1) {
    float sc = (mode == 3) ? 1.f : 2.f;
    int s = offs[v], e = offs[v + 1];
    for (int i = s; i < e; ++i) {
      int2 cw = cwc[i];
      float w = __int_as_float(cw.y) * sc;
      const float* br = b1 + (long long)((cw.x << lb) | bi) * 3;
      a0 = fmaf(w, br[0], a0); a1 = fmaf(w, br[1], a1); a2 = fmaf(w, br[2], a2);
    }
  }
  if (mode >= 2) {
    const float* p = b2o + (long long)r * 3;
    a0 -= p[0]; a1 -= p[1]; a2 -= p[2];
  }
  if (mode == 3) {
    a0 += bias[0]; a1 += bias[1]; a2 += bias[2];
    float* o = dout + ((long long)(boff + bi) * n + v) * 3;
    o[0] = a0; o[1] = a1; o[2] = a2;
  } else {
    float* o = b2o + (long long)r * 3;
    o[0] = a0; o[1] = a1; o[2] = a2;
  }
}

__global__ void linear_kernel(const float* __restrict__ x, const float* __restrict__ w,
                              const float* __restrict__ bias, float* __restrict__ out) {
  int t = gtid();
  const int TOT = 157 * 16 * 64;
  if (t >= TOT) return;
  int c = t & 63;
  int b = (t >> 6) & 15;
  int v = t >> 10;
  int colw = v * 64 + c;
  float acc = bias[colw];
  const float* xr = x + b * 128;
  for (int k = 0; k < 128; ++k) acc = fmaf(xr[k], w[k * 10048 + colw], acc);
  out[t] = acc;
}

extern "C" void kernel_launch(void* const* d_in, const int* in_sizes, int n_in,
                              void* d_out, int out_size, void* d_ws, size_t ws_size,
                              hipStream_t stream) {
  const int N[4] = {40000, 10000, 2500, 625};
  const int E[4] = {240000, 60000, 15000, 3750};
  const int NNZ[4] = {120000, 30000, 7500, 1875};
  const int DP[4] = {0, 40000, 50000, 52500};
  const int DE[4] = {53125, 93125, 103125, 105625};
  const int ITEMS = 478125;

  const float* x     = (const float*)d_in[0];
  const float* lin_w = (const float*)d_in[1];
  const float* lin_b = (const float*)d_in[2];
  const int* edge[4] = {(const int*)d_in[3], (const int*)d_in[4], (const int*)d_in[5], (const int*)d_in[6]};
  const int* up_row[4]; const int* up_col[4]; const float* up_val[4];
  for (int i = 0; i < 4; ++i) {
    up_row[i] = (const int*)d_in[7 + 3 * i];
    up_col[i] = (const int*)d_in[8 + 3 * i];
    up_val[i] = (const float*)d_in[9 + 3 * i];
  }
  const float* W_[5] = {(const float*)d_in[19], (const float*)d_in[21], (const float*)d_in[23],
                        (const float*)d_in[25], (const float*)d_in[27]};
  const float* b_[5] = {(const float*)d_in[20], (const float*)d_in[22], (const float*)d_in[24],
                        (const float*)d_in[26], (const float*)d_in[28]};

  char* ws = (char*)d_ws;
  size_t off = 0;
  auto alloc = [&](size_t bytes) -> void* {
    void* p = ws + off;
    off = (off + bytes + 255) & ~(size_t)255;
    return p;
  };
  auto cdiv = [](int a, int b) { return (a + b - 1) / b; };

  float* slot[4];
  for (int i = 0; i < 4; ++i) slot[i] = (float*)alloc(20480000ull);  // fp32 / level-1 bf16
  uint4* Ab = (uint4*)alloc(20480000ull);  // level-0 HALF bf16 X [40000][8][32]
  uint4* Bb = (uint4*)alloc(20480000ull);  // level-0 HALF state
  uint4* Cb = (uint4*)alloc(20480000ull);  // level-0 HALF state / h0 linear
  unsigned short* c_all = (unsigned short*)alloc((size_t)6 * 320000 * 3 * 2);  // 11.5 MB
  float* ob1 = (float*)alloc((size_t)320000 * 3 * 4);
  float* ob2 = (float*)alloc((size_t)320000 * 3 * 4);
  int* deg_all    = (int*)alloc(SCAN_TOT * 4);
  int* cursor_all = (int*)alloc(SCAN_TOT * 4);
  int* offs_all   = (int*)alloc((SCAN_TOT + 1) * 4);
  int* bsum       = (int*)alloc(SCAN_NB * 4);
  int2* cwc_arena = (int2*)alloc((size_t)ITEMS * 8);
  uint4* Wt2 = (uint4*)alloc(6 * 128 * 16);
  uint4* Wt3 = (uint4*)alloc(6 * 128 * 16);

  if (off > ws_size) {
    fill_kernel<<<cdiv(out_size, TB), TB, 0, stream>>>((float*)d_out, out_size,
                                                       (float)(ws_size >> 20));
    return;
  }

  // ---- batched CSR build ----
  SegD sg;
  int cum = 0;
  for (int l = 0; l < 4; ++l) {
    sg.rows[l] = up_row[l]; sg.cols[l] = up_col[l]; sg.vals[l] = up_val[l];
    sg.start[l] = cum; sg.degb[l] = DP[l]; cum += NNZ[l];
  }
  for (int l = 0; l < 4; ++l) {
    sg.rows[4 + l] = edge[l]; sg.cols[4 + l] = edge[l] + E[l]; sg.vals[4 + l] = nullptr;
    sg.start[4 + l] = cum; sg.degb[4 + l] = DE[l]; cum += E[l];
  }
  zero_int_kernel<<<cdiv(SCAN_TOT, TB), TB, 0, stream>>>(deg_all, SCAN_TOT);
  count_all_kernel<<<cdiv(ITEMS, TB), TB, 0, stream>>>(sg, ITEMS, deg_all);
  scan_phase1<<<SCAN_NB, TB, 0, stream>>>(deg_all, bsum);
  scan_phase2<<<1, 128, 0, stream>>>(bsum, offs_all + SCAN_TOT);
  scan_phase3<<<SCAN_NB, TB, 0, stream>>>(deg_all, bsum, offs_all, cursor_all);
  fill_all_kernel<<<cdiv(ITEMS, TB), TB, 0, stream>>>(sg, ITEMS, deg_all, offs_all,
                                                      cursor_all, cwc_arena);
  wconv_kernel<<<cdiv(3072, TB), TB, 0, stream>>>(W_[2], (unsigned*)Wt2);
  wconv_kernel<<<cdiv(3072, TB), TB, 0, stream>>>(W_[3], (unsigned*)Wt3);

  // latent -> h4 [157][16][64]
  linear_kernel<<<cdiv(157 * 16 * 64, TB), TB, 0, stream>>>(x, lin_w, lin_b, slot[0]);
  float* H = slot[0];
  float* A = slot[1];
  float* B = slot[2];
  float* C = slot[3];

  const int CINA[2]  = {64, 64};
  const int COUTA[2] = {64, 32};

  // ---- deblocks j=0,1 on meshes 3,2 (fp32, BI=16) ----
  for (int j = 0; j < 2; ++j) {
    int lvl = 3 - j;
    int n = N[lvl];
    int cin = CINA[j], cout = COUTA[j];
    int os4 = 16 * cin / 4;
    int osh = (os4 == 256) ? 8 : 7;
    const int* offs_p = offs_all + DP[lvl];
    const int* offs_e = offs_all + DE[lvl];

    pool_kernel<<<cdiv(n * os4, TB), TB, 0, stream>>>(
        (const float4*)H, offs_p, cwc_arena, (float4*)A, n, os4, 0, os4, osh);

    int cs = cout / 8;
    dim3 g(cdiv(n * 16 * cs, TB));
    auto step = [&](const float* b1, float* b2o, int k, int mode) {
      const float* Wk = W_[j] + (size_t)k * cin * cout;
      if (cin == 64 && cout == 64)
        hipLaunchKernelGGL((cheb_step_kernel<64, 64>), g, dim3(TB), 0, stream,
                           A, b1, b2o, Wk, b_[j], offs_e, cwc_arena, n, 4, mode);
      else
        hipLaunchKernelGGL((cheb_step_kernel<64, 32>), g, dim3(TB), 0, stream,
                           A, b1, b2o, Wk, b_[j], offs_e, cwc_arena, n, 4, mode);
    };
    step(nullptr, B, 5, 0);
    step(B, C, 4, 1);
    step(C, B, 3, 2);
    step(B, C, 2, 2);
    step(C, B, 1, 2);
    step(B, C, 0, 3);

    float* tmp = H; H = C; C = tmp;
  }

  // ---- deblock j=2 on mesh 1 via fused pool+MFMA Clenshaw (bf16, full batch R=16) ----
  uint4* Ab1 = (uint4*)A;
  uint4* Bb1 = (uint4*)B;
  uint4* Cb1 = (uint4*)C;
  {
    int n = N[1];  // 10000
    dim3 gmf(n / 4);
    hipLaunchKernelGGL((pool_mfma_kernel<0, 16>), gmf, dim3(256), 0, stream,
                       (const void*)H, offs_all + DP[1], cwc_arena,
                       Ab1, Bb1, Wt2 + (size_t)5 * 128, 0, n);
    auto dstep = [&](const uint4* b1, uint4* b2o, int k, int mode) {
      hipLaunchKernelGGL((cheb_mfma32_kernel<16>), gmf, dim3(256), 0, stream,
                         Ab1, b1, b2o, Wt2 + (size_t)k * 128, b_[2],
                         offs_all + DE[1], cwc_arena, n, mode);
    };
    dstep(Bb1, Cb1, 4, 1);
    dstep(Cb1, Bb1, 3, 2);
    dstep(Bb1, Cb1, 2, 2);
    dstep(Cb1, Bb1, 1, 2);
    dstep(Bb1, Cb1, 0, 3);   // h1 linear bf16 [10000][16][32] in Cb1
  }

  // ---- level 0: batch-split (2 x 8), fused pool+MFMA Clenshaw + out conv ----
  {
    int n = N[0];
    int nr = n * 8;
    const int* offs_p = offs_all + DP[0];
    const int* offs_e = offs_all + DE[0];
    dim3 gmf(n / 8);          // 5000 blocks: 4 waves x 2 vertices
    dim3 gr(cdiv(nr, TB));
    float* dout = (float*)d_out;

    for (int bg = 0; bg < 2; ++bg) {
      hipLaunchKernelGGL((pool_mfma_kernel<1, 8>), gmf, dim3(256), 0, stream,
                         (const void*)Cb1, offs_p, cwc_arena,
                         Ab, Bb, Wt3 + (size_t)5 * 128, bg * 8, n);
      auto dstep = [&](const uint4* b1, uint4* b2o, int k, int mode) {
        hipLaunchKernelGGL((cheb_mfma32_kernel<8>), gmf, dim3(256), 0, stream,
                           Ab, b1, b2o, Wt3 + (size_t)k * 128, b_[3],
                           offs_e, cwc_arena, n, mode);
      };
      dstep(Bb, Cb, 4, 1);
      dstep(Cb, Bb, 3, 2);
      dstep(Bb, Cb, 2, 2);
      dstep(Cb, Bb, 1, 2);
      dstep(Bb, Cb, 0, 3);   // h0 half, linear bf16 [40000][8][32] in Cb

      gemm_out_all_kernel<<<gr, dim3(TB), 0, stream>>>((const uint4*)Cb, W_[4], c_all, nr);
      auto ostep = [&](const float* b1, float* b2o, int k, int mode) {
        cheb_out_step_kernel<<<gr, dim3(TB), 0, stream>>>(
            c_all, k, b1, b2o, b_[4], offs_e, cwc_arena, n, 3, bg * 8, dout, mode);
      };
      ostep(nullptr, ob1, 5, 0);
      ostep(ob1, ob2, 4, 1);
      ostep(ob2, ob1, 3, 2);
      ostep(ob1, ob2, 2, 2);
      ostep(ob2, ob1, 1, 2);
      ostep(ob1, ob2, 0, 3);
    }
  }
}

// Round 14
// 748.814 us; speedup vs baseline: 1.1037x; 1.1037x over previous
//
#include <hip/hip_runtime.h>
#include <math.h>

#define TB 256
#define SCAN_TOT 106250
#define SCAN_NB  104

typedef __bf16 bf16x8 __attribute__((ext_vector_type(8)));
typedef float f32x4 __attribute__((ext_vector_type(4)));
typedef float f32x2 __attribute__((ext_vector_type(2)));

static __device__ __forceinline__ int gtid() { return blockIdx.x * blockDim.x + threadIdx.x; }

static __device__ __forceinline__ void fma4(float4& a, float s, const float4 b) {
  a.x = fmaf(s, b.x, a.x); a.y = fmaf(s, b.y, a.y);
  a.z = fmaf(s, b.z, a.z); a.w = fmaf(s, b.w, a.w);
}

static __device__ __forceinline__ float bfus(unsigned short u) {
  union { unsigned u; float f; } c; c.u = ((unsigned)u) << 16; return c.f;
}
static __device__ __forceinline__ unsigned pk2(float a, float b) {
  union { unsigned u; __bf16 h[2]; } c;
  c.h[0] = (__bf16)a; c.h[1] = (__bf16)b;
  return c.u;
}
static __device__ __forceinline__ unsigned short us1(float a) {
  union { unsigned short u; __bf16 h; } c; c.h = (__bf16)a; return c.u;
}
static __device__ __forceinline__ f32x2 unpk(unsigned u) {
  union { unsigned u; float f; } lo, hi;
  lo.u = u << 16; hi.u = u & 0xffff0000u;
  f32x2 r; r.x = lo.f; r.y = hi.f; return r;
}

__global__ void fill_kernel(float* __restrict__ p, int n, float v) {
  int i = gtid(); if (i < n) p[i] = v;
}

__global__ void zero_int_kernel(int* __restrict__ p, int n) {
  int i = gtid(); if (i < n) p[i] = 0;
}

struct SegD {
  const int* rows[8];
  const int* cols[8];
  const float* vals[8];  // null => edge seg (compute sym-norm weight)
  int start[8];
  int degb[8];
};

__global__ void count_all_kernel(SegD sg, int total, int* __restrict__ deg) {
  int t = gtid(); if (t >= total) return;
  int seg = 0;
  #pragma unroll
  for (int q = 1; q < 8; ++q) seg += (t >= sg.start[q]);
  int i = t - sg.start[seg];
  atomicAdd(&deg[sg.degb[seg] + sg.rows[seg][i]], 1);
}

// fused (col, weight-bits) CSR arena
__global__ void fill_all_kernel(SegD sg, int total, const int* __restrict__ deg,
                                const int* __restrict__ offs, int* __restrict__ cursor,
                                int2* __restrict__ cwc) {
  int t = gtid(); if (t >= total) return;
  int seg = 0;
  #pragma unroll
  for (int q = 1; q < 8; ++q) seg += (t >= sg.start[q]);
  int i = t - sg.start[seg];
  int db = sg.degb[seg];
  int r = sg.rows[seg][i];
  int c = sg.cols[seg][i];
  int p = atomicAdd(&cursor[db + r], 1);
  int idx = offs[db + r] + p;
  float w;
  if (sg.vals[seg]) {
    w = sg.vals[seg][i];
  } else {
    int dc = deg[db + c];
    w = rsqrtf((float)deg[db + r]) * (dc > 0 ? rsqrtf((float)dc) : 0.f);
  }
  int2 o; o.x = c; o.y = __float_as_int(w);
  cwc[idx] = o;
}

// ---- 3-phase global exclusive scan over deg ----
__global__ void scan_phase1(const int* __restrict__ in, int* __restrict__ bsum) {
  __shared__ int wsum[4];
  int blk = blockIdx.x, t = threadIdx.x;
  int base = blk * 1024 + t * 4;
  int s = 0;
  #pragma unroll
  for (int q = 0; q < 4; ++q) { int i = base + q; if (i < SCAN_TOT) s += in[i]; }
  #pragma unroll
  for (int o = 32; o > 0; o >>= 1) s += __shfl_xor(s, o, 64);
  int lane = t & 63, wid = t >> 6;
  if (lane == 0) wsum[wid] = s;
  __syncthreads();
  if (t == 0) bsum[blk] = wsum[0] + wsum[1] + wsum[2] + wsum[3];
}

__global__ void scan_phase2(int* __restrict__ bsum, int* __restrict__ offs_end) {
  int t = threadIdx.x;  // 128
  int v = (t < SCAN_NB) ? bsum[t] : 0;
  int lane = t & 63, wid = t >> 6;
  int p = v;
  #pragma unroll
  for (int o = 1; o < 64; o <<= 1) { int u = __shfl_up(p, o, 64); if (lane >= o) p += u; }
  __shared__ int w0tot;
  if (wid == 0 && lane == 63) w0tot = p;
  __syncthreads();
  int incl = p + (wid ? w0tot : 0);
  if (t < SCAN_NB) bsum[t] = incl - v;
  if (t == 127) offs_end[0] = incl;
}

__global__ void scan_phase3(const int* __restrict__ in, const int* __restrict__ bbase,
                            int* __restrict__ offs, int* __restrict__ cursor) {
  __shared__ int wsum[4];
  int blk = blockIdx.x, t = threadIdx.x;
  int base = blk * 1024 + t * 4;
  int v[4]; int s = 0;
  #pragma unroll
  for (int q = 0; q < 4; ++q) { int i = base + q; v[q] = (i < SCAN_TOT) ? in[i] : 0; s += v[q]; }
  int lane = t & 63, wid = t >> 6;
  int p = s;
  #pragma unroll
  for (int o = 1; o < 64; o <<= 1) { int u = __shfl_up(p, o, 64); if (lane >= o) p += u; }
  if (lane == 63) wsum[wid] = p;
  __syncthreads();
  int woff = 0;
  #pragma unroll
  for (int q = 0; q < 4; ++q) woff += (q < wid) ? wsum[q] : 0;
  int ex = bbase[blk] + woff + p - s;
  #pragma unroll
  for (int q = 0; q < 4; ++q) {
    int i = base + q;
    if (i < SCAN_TOT) { offs[i] = ex; cursor[i] = 0; ex += v[q]; }
  }
}

// W [6][32k][32col] f32 -> Wt bf16 [6][32col][32k] (packed pairs of k)
__global__ void wconv_kernel(const float* __restrict__ W, unsigned* __restrict__ Wt) {
  int p = gtid();
  if (p >= 6 * 32 * 16) return;
  int kk2 = p & 15;
  int col = (p >> 4) & 31;
  int kidx = p >> 9;
  float v0 = W[kidx * 1024 + (2 * kk2) * 32 + col];
  float v1 = W[kidx * 1024 + (2 * kk2 + 1) * 32 + col];
  Wt[(kidx * 32 + col) * 16 + kk2] = pk2(v0, v1);
}

// ---- fp32 pool (upper levels) ----
__global__ void pool_kernel(const float4* __restrict__ x, const int* __restrict__ offs,
                            const int2* __restrict__ cwc,
                            float4* __restrict__ out, int n, int xs4, int xoff4,
                            int os4, int osh) {
  int t = gtid();
  if (t >= n * os4) return;
  int v = t >> osh, j = t & (os4 - 1);
  int s = offs[v], e = offs[v + 1];
  float4 a = {0.f, 0.f, 0.f, 0.f};
  for (int i = s; i < e; ++i) {
    int2 cw = cwc[i];
    fma4(a, __int_as_float(cw.y), x[(long long)cw.x * xs4 + xoff4 + j]);
  }
  out[t] = a;
}

// ---- Fused pool + Clenshaw step k=5 (mode 0), one wave per vertex ----
// 4-deep prefetched gather (pool degree avg 3). Lane (g,c15) accumulates its
// A-frag; store X linear; 2 MFMAs; b5 in lane-blocked layout.
// SRC 0: x = fp32 [u][16][32]; SRC 1: x = bf16 linear uint4 [u*64]
template<int SRC>
__global__ void __launch_bounds__(256)
pool_mfma_kernel(const void* __restrict__ xsrc, const int* __restrict__ offs,
                 const int2* __restrict__ cwc,
                 uint4* __restrict__ Xout, uint4* __restrict__ b5out,
                 const uint4* __restrict__ Wtk5, int n) {
  int lane = threadIdx.x & 63;
  int v = (blockIdx.x << 2) | (threadIdx.x >> 6);
  if (v >= n) return;
  int g = lane >> 4, c15 = lane & 15;
  int s = offs[v], e = offs[v + 1];
  int deg = e - s;
  float a[8];
  #pragma unroll
  for (int q = 0; q < 8; ++q) a[q] = 0.f;

  if (deg > 0) {
    if (SRC == 0) {
      const float4* x = (const float4*)xsrc;
      float4 x0[4], x1[4]; float ww[4];
      #pragma unroll
      for (int p = 0; p < 4; ++p) {
        int idx = s + (p < deg ? p : 0);
        int2 cw = cwc[idx];
        ww[p] = (p < deg) ? __int_as_float(cw.y) : 0.f;
        const float4* xr = x + (long long)cw.x * 128 + c15 * 8 + g * 2;
        x0[p] = xr[0]; x1[p] = xr[1];
      }
      #pragma unroll
      for (int p = 0; p < 4; ++p) {
        float w = ww[p];
        a[0] = fmaf(w, x0[p].x, a[0]); a[1] = fmaf(w, x0[p].y, a[1]);
        a[2] = fmaf(w, x0[p].z, a[2]); a[3] = fmaf(w, x0[p].w, a[3]);
        a[4] = fmaf(w, x1[p].x, a[4]); a[5] = fmaf(w, x1[p].y, a[5]);
        a[6] = fmaf(w, x1[p].z, a[6]); a[7] = fmaf(w, x1[p].w, a[7]);
      }
      for (int i = s + 4; i < e; ++i) {
        int2 cw = cwc[i];
        float w = __int_as_float(cw.y);
        const float4* xr = x + (long long)cw.x * 128 + c15 * 8 + g * 2;
        float4 y0 = xr[0], y1 = xr[1];
        a[0] = fmaf(w, y0.x, a[0]); a[1] = fmaf(w, y0.y, a[1]);
        a[2] = fmaf(w, y0.z, a[2]); a[3] = fmaf(w, y0.w, a[3]);
        a[4] = fmaf(w, y1.x, a[4]); a[5] = fmaf(w, y1.y, a[5]);
        a[6] = fmaf(w, y1.z, a[6]); a[7] = fmaf(w, y1.w, a[7]);
      }
    } else {
      const uint4* x = (const uint4*)xsrc;
      uint4 bv[4]; float ww[4];
      #pragma unroll
      for (int p = 0; p < 4; ++p) {
        int idx = s + (p < deg ? p : 0);
        int2 cw = cwc[idx];
        ww[p] = (p < deg) ? __int_as_float(cw.y) : 0.f;
        bv[p] = x[(long long)cw.x * 64 + c15 * 4 + g];
      }
      #pragma unroll
      for (int p = 0; p < 4; ++p) {
        f32x2 w2 = {ww[p], ww[p]};
        f32x2 r0 = __builtin_elementwise_fma(w2, unpk(bv[p].x), f32x2{a[0], a[1]});
        f32x2 r1 = __builtin_elementwise_fma(w2, unpk(bv[p].y), f32x2{a[2], a[3]});
        f32x2 r2 = __builtin_elementwise_fma(w2, unpk(bv[p].z), f32x2{a[4], a[5]});
        f32x2 r3 = __builtin_elementwise_fma(w2, unpk(bv[p].w), f32x2{a[6], a[7]});
        a[0] = r0.x; a[1] = r0.y; a[2] = r1.x; a[3] = r1.y;
        a[4] = r2.x; a[5] = r2.y; a[6] = r3.x; a[7] = r3.y;
      }
      for (int i = s + 4; i < e; ++i) {
        int2 cw = cwc[i];
        float w = __int_as_float(cw.y);
        f32x2 w2 = {w, w};
        uint4 xv = x[(long long)cw.x * 64 + c15 * 4 + g];
        f32x2 r0 = __builtin_elementwise_fma(w2, unpk(xv.x), f32x2{a[0], a[1]});
        f32x2 r1 = __builtin_elementwise_fma(w2, unpk(xv.y), f32x2{a[2], a[3]});
        f32x2 r2 = __builtin_elementwise_fma(w2, unpk(xv.z), f32x2{a[4], a[5]});
        f32x2 r3 = __builtin_elementwise_fma(w2, unpk(xv.w), f32x2{a[6], a[7]});
        a[0] = r0.x; a[1] = r0.y; a[2] = r1.x; a[3] = r1.y;
        a[4] = r2.x; a[5] = r2.y; a[6] = r3.x; a[7] = r3.y;
      }
    }
  }
  union { uint4 u; bf16x8 b; } Au;
  Au.u.x = pk2(a[0], a[1]); Au.u.y = pk2(a[2], a[3]);
  Au.u.z = pk2(a[4], a[5]); Au.u.w = pk2(a[6], a[7]);
  Xout[(long long)v * 64 + c15 * 4 + g] = Au.u;

  union { uint4 u; bf16x8 b; } B0u, B1u;
  B0u.u = Wtk5[c15 * 4 + g];
  B1u.u = Wtk5[(16 + c15) * 4 + g];
  f32x4 z = {0.f, 0.f, 0.f, 0.f};
  f32x4 m0 = __builtin_amdgcn_mfma_f32_16x16x32_bf16(Au.b, B0u.b, z, 0, 0, 0);
  f32x4 m1 = __builtin_amdgcn_mfma_f32_16x16x32_bf16(Au.b, B1u.b, z, 0, 0, 0);
  uint4 o;
  o.x = pk2(m0[0], m1[0]); o.y = pk2(m0[1], m1[1]);
  o.z = pk2(m0[2], m1[2]); o.w = pk2(m0[3], m1[3]);
  b5out[(long long)v * 64 + g * 16 + c15] = o;
}

// ---- fp32 channel-split Clenshaw step (upper levels j=0,1) ----
template<int CIN, int COUT>
__global__ void cheb_step_kernel(const float* __restrict__ X,
                                 const float* __restrict__ b1,
                                 float* __restrict__ b2o,
                                 const float* __restrict__ Wk,
                                 const float* __restrict__ bias,
                                 const int* __restrict__ offs,
                                 const int2* __restrict__ cwc,
                                 int n, int LB, int mode) {
  constexpr int CS = COUT / 8;
  constexpr int LCS = (CS == 8) ? 3 : 2;
  constexpr int W4 = COUT / 4;
  __shared__ float sW[CIN * COUT];
  for (int i = threadIdx.x; i < CIN * COUT; i += blockDim.x) sW[i] = Wk[i];
  __syncthreads();
  int t = gtid();
  int BI = 1 << LB;
  if (t >= n * BI * CS) return;
  int cs = t & (CS - 1);
  int r = t >> LCS;
  int v = r >> LB;
  int bi = r & (BI - 1);
  float4 a0 = {0.f, 0.f, 0.f, 0.f}, a1 = {0.f, 0.f, 0.f, 0.f};
  const float4* Xr = (const float4*)(X + (long long)r * CIN);
  const float4* wbase = ((const float4*)sW) + cs * 2;
  #pragma unroll
  for (int c4 = 0; c4 < CIN / 4; ++c4) {
    float4 xv = Xr[c4];
    const float4* w = wbase + (c4 * 4) * W4;
    fma4(a0, xv.x, w[0]); fma4(a1, xv.x, w[1]); w += W4;
    fma4(a0, xv.y, w[0]); fma4(a1, xv.y, w[1]); w += W4;
    fma4(a0, xv.z, w[0]); fma4(a1, xv.z, w[1]); w += W4;
    fma4(a0, xv.w, w[0]); fma4(a1, xv.w, w[1]);
  }
  if (mode >= 1) {
    float sc = (mode == 3) ? 1.f : 2.f;
    int s = offs[v], e = offs[v + 1];
    const float4* b14 = (const float4*)b1;
    for (int i = s; i < e; ++i) {
      int2 cw = cwc[i];
      float w = __int_as_float(cw.y) * sc;
      long long rb = (long long)((cw.x << LB) | bi) * W4 + cs * 2;
      fma4(a0, w, b14[rb]); fma4(a1, w, b14[rb + 1]);
    }
  }
  float4* Or = ((float4*)b2o) + (long long)r * W4 + cs * 2;
  if (mode >= 2) {
    float4 p0 = Or[0], p1 = Or[1];
    a0.x -= p0.x; a0.y -= p0.y; a0.z -= p0.z; a0.w -= p0.w;
    a1.x -= p1.x; a1.y -= p1.y; a1.z -= p1.z; a1.w -= p1.w;
  }
  if (mode == 3) {
    const float* bs = bias + cs * 8;
    a0.x += bs[0]; a0.y += bs[1]; a0.z += bs[2]; a0.w += bs[3];
    a1.x += bs[4]; a1.y += bs[5]; a1.z += bs[6]; a1.w += bs[7];
    a0.x = a0.x > 0.f ? a0.x : expm1f(a0.x);
    a0.y = a0.y > 0.f ? a0.y : expm1f(a0.y);
    a0.z = a0.z > 0.f ? a0.z : expm1f(a0.z);
    a0.w = a0.w > 0.f ? a0.w : expm1f(a0.w);
    a1.x = a1.x > 0.f ? a1.x : expm1f(a1.x);
    a1.y = a1.y > 0.f ? a1.y : expm1f(a1.y);
    a1.z = a1.z > 0.f ? a1.z : expm1f(a1.z);
    a1.w = a1.w > 0.f ? a1.w : expm1f(a1.w);
  }
  Or[0] = a0; Or[1] = a1;
}

// ---- MFMA Clenshaw step (CIN=COUT=32, BI=16): one wave per vertex ----
// 8-deep prefetched gather (edge degree avg 6, wave-uniform).
// State b1/b2o: lane-blocked interleaved — uint4 @ u*64 + g*16 + c15.
// mode 3 writes LINEAR bf16 into b2o (own-row in-place safe).
__global__ void __launch_bounds__(256)
cheb_mfma32_kernel(const uint4* __restrict__ X,
                   const uint4* __restrict__ b1,
                   uint4* __restrict__ b2o,
                   const uint4* __restrict__ Wtk,
                   const float* __restrict__ bias,
                   const int* __restrict__ offs,
                   const int2* __restrict__ cwc,
                   int n, int mode) {
  int lane = threadIdx.x & 63;
  int v = (blockIdx.x << 2) | (threadIdx.x >> 6);
  if (v >= n) return;
  int g = lane >> 4;
  int c15 = lane & 15;

  union { uint4 u; bf16x8 b; } Au, B0u, B1u;
  Au.u = X[(long long)v * 64 + c15 * 4 + g];
  B0u.u = Wtk[c15 * 4 + g];
  B1u.u = Wtk[(16 + c15) * 4 + g];

  f32x4 z = {0.f, 0.f, 0.f, 0.f};
  f32x4 m0 = __builtin_amdgcn_mfma_f32_16x16x32_bf16(Au.b, B0u.b, z, 0, 0, 0);
  f32x4 m1 = __builtin_amdgcn_mfma_f32_16x16x32_bf16(Au.b, B1u.b, z, 0, 0, 0);
  f32x2 acc[4];
  #pragma unroll
  for (int q = 0; q < 4; ++q) { acc[q].x = m0[q]; acc[q].y = m1[q]; }

  long long own = (long long)v * 64 + g * 16 + c15;
  if (mode >= 1) {
    float sc = (mode == 3) ? 1.f : 2.f;
    int s = offs[v], e = offs[v + 1];
    int deg = e - s;
    if (deg > 0) {
      uint4 bv[8]; float ww[8];
      #pragma unroll
      for (int p = 0; p < 8; ++p) {
        int idx = s + (p < deg ? p : 0);
        int2 cw = cwc[idx];
        ww[p] = (p < deg) ? __int_as_float(cw.y) * sc : 0.f;
        bv[p] = b1[(long long)cw.x * 64 + g * 16 + c15];
      }
      #pragma unroll
      for (int p = 0; p < 8; ++p) {
        f32x2 w2 = {ww[p], ww[p]};
        acc[0] = __builtin_elementwise_fma(w2, unpk(bv[p].x), acc[0]);
        acc[1] = __builtin_elementwise_fma(w2, unpk(bv[p].y), acc[1]);
        acc[2] = __builtin_elementwise_fma(w2, unpk(bv[p].z), acc[2]);
        acc[3] = __builtin_elementwise_fma(w2, unpk(bv[p].w), acc[3]);
      }
      for (int i = s + 8; i < e; ++i) {
        int2 cw = cwc[i];
        float w = __int_as_float(cw.y) * sc;
        f32x2 w2 = {w, w};
        uint4 xv = b1[(long long)cw.x * 64 + g * 16 + c15];
        acc[0] = __builtin_elementwise_fma(w2, unpk(xv.x), acc[0]);
        acc[1] = __builtin_elementwise_fma(w2, unpk(xv.y), acc[1]);
        acc[2] = __builtin_elementwise_fma(w2, unpk(xv.z), acc[2]);
        acc[3] = __builtin_elementwise_fma(w2, unpk(xv.w), acc[3]);
      }
    }
  }
  if (mode >= 2) {
    uint4 pv = b2o[own];
    acc[0] -= unpk(pv.x); acc[1] -= unpk(pv.y);
    acc[2] -= unpk(pv.z); acc[3] -= unpk(pv.w);
  }
  if (mode == 3) {
    float bs0 = bias[c15], bs1 = bias[16 + c15];
    unsigned short* o = (unsigned short*)b2o;
    long long lb = ((long long)v * 16 + 4 * g) * 32;
    #pragma unroll
    for (int q = 0; q < 4; ++q) {
      float a = acc[q].x + bs0;
      float b = acc[q].y + bs1;
      a = a > 0.f ? a : expm1f(a);
      b = b > 0.f ? b : expm1f(b);
      o[lb + q * 32 + c15] = us1(a);
      o[lb + q * 32 + 16 + c15] = us1(b);
    }
  } else {
    uint4 o;
    o.x = pk2(acc[0].x, acc[0].y); o.y = pk2(acc[1].x, acc[1].y);
    o.z = pk2(acc[2].x, acc[2].y); o.w = pk2(acc[3].x, acc[3].y);
    b2o[own] = o;
  }
}

// c_all[k][r][3] (bf16) = X[r]·Wout[k], X linear bf16 [r][32], r over n*16
__global__ void gemm_out_all_kernel(const uint4* __restrict__ X, const float* __restrict__ W,
                                    unsigned short* __restrict__ c_all, int nr) {
  __shared__ float sW[576];
  for (int i = threadIdx.x; i < 576; i += blockDim.x) sW[i] = W[i];
  __syncthreads();
  int r = gtid();
  if (r >= nr) return;
  const uint4* Xr = X + (long long)r * 4;
  float xa[32];
  #pragma unroll
  for (int q = 0; q < 4; ++q) {
    uint4 xv = Xr[q];
    f32x2 p0 = unpk(xv.x), p1 = unpk(xv.y), p2 = unpk(xv.z), p3 = unpk(xv.w);
    xa[q * 8 + 0] = p0.x; xa[q * 8 + 1] = p0.y;
    xa[q * 8 + 2] = p1.x; xa[q * 8 + 3] = p1.y;
    xa[q * 8 + 4] = p2.x; xa[q * 8 + 5] = p2.y;
    xa[q * 8 + 6] = p3.x; xa[q * 8 + 7] = p3.y;
  }
  float acc[18];
  #pragma unroll
  for (int i = 0; i < 18; ++i) acc[i] = 0.f;
  #pragma unroll
  for (int c = 0; c < 32; ++c) {
    float xc = xa[c];
    #pragma unroll
    for (int k = 0; k < 6; ++k) {
      acc[k * 3 + 0] = fmaf(xc, sW[k * 96 + c * 3 + 0], acc[k * 3 + 0]);
      acc[k * 3 + 1] = fmaf(xc, sW[k * 96 + c * 3 + 1], acc[k * 3 + 1]);
      acc[k * 3 + 2] = fmaf(xc, sW[k * 96 + c * 3 + 2], acc[k * 3 + 2]);
    }
  }
  #pragma unroll
  for (int k = 0; k < 6; ++k) {
    unsigned short* o = c_all + ((long long)k * nr + r) * 3;
    o[0] = us1(acc[k * 3 + 0]);
    o[1] = us1(acc[k * 3 + 1]);
    o[2] = us1(acc[k * 3 + 2]);
  }
}

// Clenshaw on tiny 3-ch buffers, full batch; r = v*16+bi; mode3 -> dout[(bi*n+v)*3]
__global__ void cheb_out_step_kernel(const unsigned short* __restrict__ c_all, int k,
                                     const float* __restrict__ b1,
                                     float* __restrict__ b2o,
                                     const float* __restrict__ bias,
                                     const int* __restrict__ offs,
                                     const int2* __restrict__ cwc,
                                     int n, float* __restrict__ dout, int mode) {
  int r = gtid();
  if (r >= n * 16) return;
  int v = r >> 4, bi = r & 15;
  const unsigned short* cr = c_all + ((long long)k * n * 16 + r) * 3;
  float a0 = bfus(cr[0]), a1 = bfus(cr[1]), a2 = bfus(cr[2]);
  if (mode >= 1) {
    float sc = (mode == 3) ? 1.f : 2.f;
    int s = offs[v], e = offs[v + 1];
    for (int i = s; i < e; ++i) {
      int2 cw = cwc[i];
      float w = __int_as_float(cw.y) * sc;
      const float* br = b1 + (long long)((cw.x << 4) | bi) * 3;
      a0 = fmaf(w, br[0], a0); a1 = fmaf(w, br[1], a1); a2 = fmaf(w, br[2], a2);
    }
  }
  if (mode >= 2) {
    const float* p = b2o + (long long)r * 3;
    a0 -= p[0]; a1 -= p[1]; a2 -= p[2];
  }
  if (mode == 3) {
    a0 += bias[0]; a1 += bias[1]; a2 += bias[2];
    float* o = dout + ((long long)bi * n + v) * 3;
    o[0] = a0; o[1] = a1; o[2] = a2;
  } else {
    float* o = b2o + (long long)r * 3;
    o[0] = a0; o[1] = a1; o[2] = a2;
  }
}

__global__ void linear_kernel(const float* __restrict__ x, const float* __restrict__ w,
                              const float* __restrict__ bias, float* __restrict__ out) {
  int t = gtid();
  const int TOT = 157 * 16 * 64;
  if (t >= TOT) return;
  int c = t & 63;
  int b = (t >> 6) & 15;
  int v = t >> 10;
  int colw = v * 64 + c;
  float acc = bias[colw];
  const float* xr = x + b * 128;
  for (int k = 0; k < 128; ++k) acc = fmaf(xr[k], w[k * 10048 + colw], acc);
  out[t] = acc;
}

extern "C" void kernel_launch(void* const* d_in, const int* in_sizes, int n_in,
                              void* d_out, int out_size, void* d_ws, size_t ws_size,
                              hipStream_t stream) {
  const int N[4] = {40000, 10000, 2500, 625};
  const int E[4] = {240000, 60000, 15000, 3750};
  const int NNZ[4] = {120000, 30000, 7500, 1875};
  const int DP[4] = {0, 40000, 50000, 52500};
  const int DE[4] = {53125, 93125, 103125, 105625};
  const int ITEMS = 478125;

  const float* x     = (const float*)d_in[0];
  const float* lin_w = (const float*)d_in[1];
  const float* lin_b = (const float*)d_in[2];
  const int* edge[4] = {(const int*)d_in[3], (const int*)d_in[4], (const int*)d_in[5], (const int*)d_in[6]};
  const int* up_row[4]; const int* up_col[4]; const float* up_val[4];
  for (int i = 0; i < 4; ++i) {
    up_row[i] = (const int*)d_in[7 + 3 * i];
    up_col[i] = (const int*)d_in[8 + 3 * i];
    up_val[i] = (const float*)d_in[9 + 3 * i];
  }
  const float* W_[5] = {(const float*)d_in[19], (const float*)d_in[21], (const float*)d_in[23],
                        (const float*)d_in[25], (const float*)d_in[27]};
  const float* b_[5] = {(const float*)d_in[20], (const float*)d_in[22], (const float*)d_in[24],
                        (const float*)d_in[26], (const float*)d_in[28]};

  char* ws = (char*)d_ws;
  size_t off = 0;
  auto alloc = [&](size_t bytes) -> void* {
    void* p = ws + off;
    off = (off + bytes + 255) & ~(size_t)255;
    return p;
  };
  auto cdiv = [](int a, int b) { return (a + b - 1) / b; };

  float* slot[4];
  for (int i = 0; i < 4; ++i) slot[i] = (float*)alloc(20480000ull);  // fp32 / level-1 bf16
  uint4* Ab = (uint4*)alloc(40960000ull);  // level-0 bf16 X (linear)
  uint4* Bb = (uint4*)alloc(40960000ull);  // level-0 state
  uint4* Cb = (uint4*)alloc(40960000ull);  // level-0 state / h0 linear
  unsigned short* c_all = (unsigned short*)alloc((size_t)6 * 640000 * 3 * 2);  // 23 MB
  float* ob1 = (float*)alloc((size_t)640000 * 3 * 4);
  float* ob2 = (float*)alloc((size_t)640000 * 3 * 4);
  int* deg_all    = (int*)alloc(SCAN_TOT * 4);
  int* cursor_all = (int*)alloc(SCAN_TOT * 4);
  int* offs_all   = (int*)alloc((SCAN_TOT + 1) * 4);
  int* bsum       = (int*)alloc(SCAN_NB * 4);
  int2* cwc_arena = (int2*)alloc((size_t)ITEMS * 8);
  uint4* Wt2 = (uint4*)alloc(6 * 128 * 16);
  uint4* Wt3 = (uint4*)alloc(6 * 128 * 16);

  if (off > ws_size) {
    fill_kernel<<<cdiv(out_size, TB), TB, 0, stream>>>((float*)d_out, out_size,
                                                       (float)(ws_size >> 20));
    return;
  }

  // ---- batched CSR build ----
  SegD sg;
  int cum = 0;
  for (int l = 0; l < 4; ++l) {
    sg.rows[l] = up_row[l]; sg.cols[l] = up_col[l]; sg.vals[l] = up_val[l];
    sg.start[l] = cum; sg.degb[l] = DP[l]; cum += NNZ[l];
  }
  for (int l = 0; l < 4; ++l) {
    sg.rows[4 + l] = edge[l]; sg.cols[4 + l] = edge[l] + E[l]; sg.vals[4 + l] = nullptr;
    sg.start[4 + l] = cum; sg.degb[4 + l] = DE[l]; cum += E[l];
  }
  zero_int_kernel<<<cdiv(SCAN_TOT, TB), TB, 0, stream>>>(deg_all, SCAN_TOT);
  count_all_kernel<<<cdiv(ITEMS, TB), TB, 0, stream>>>(sg, ITEMS, deg_all);
  scan_phase1<<<SCAN_NB, TB, 0, stream>>>(deg_all, bsum);
  scan_phase2<<<1, 128, 0, stream>>>(bsum, offs_all + SCAN_TOT);
  scan_phase3<<<SCAN_NB, TB, 0, stream>>>(deg_all, bsum, offs_all, cursor_all);
  fill_all_kernel<<<cdiv(ITEMS, TB), TB, 0, stream>>>(sg, ITEMS, deg_all, offs_all,
                                                      cursor_all, cwc_arena);
  wconv_kernel<<<cdiv(3072, TB), TB, 0, stream>>>(W_[2], (unsigned*)Wt2);
  wconv_kernel<<<cdiv(3072, TB), TB, 0, stream>>>(W_[3], (unsigned*)Wt3);

  // latent -> h4 [157][16][64]
  linear_kernel<<<cdiv(157 * 16 * 64, TB), TB, 0, stream>>>(x, lin_w, lin_b, slot[0]);
  float* H = slot[0];
  float* A = slot[1];
  float* B = slot[2];
  float* C = slot[3];

  const int CINA[2]  = {64, 64};
  const int COUTA[2] = {64, 32};

  // ---- deblocks j=0,1 on meshes 3,2 (fp32, BI=16) ----
  for (int j = 0; j < 2; ++j) {
    int lvl = 3 - j;
    int n = N[lvl];
    int cin = CINA[j], cout = COUTA[j];
    int os4 = 16 * cin / 4;
    int osh = (os4 == 256) ? 8 : 7;
    const int* offs_p = offs_all + DP[lvl];
    const int* offs_e = offs_all + DE[lvl];

    pool_kernel<<<cdiv(n * os4, TB), TB, 0, stream>>>(
        (const float4*)H, offs_p, cwc_arena, (float4*)A, n, os4, 0, os4, osh);

    int cs = cout / 8;
    dim3 g(cdiv(n * 16 * cs, TB));
    auto step = [&](const float* b1, float* b2o, int k, int mode) {
      const float* Wk = W_[j] + (size_t)k * cin * cout;
      if (cin == 64 && cout == 64)
        hipLaunchKernelGGL((cheb_step_kernel<64, 64>), g, dim3(TB), 0, stream,
                           A, b1, b2o, Wk, b_[j], offs_e, cwc_arena, n, 4, mode);
      else
        hipLaunchKernelGGL((cheb_step_kernel<64, 32>), g, dim3(TB), 0, stream,
                           A, b1, b2o, Wk, b_[j], offs_e, cwc_arena, n, 4, mode);
    };
    step(nullptr, B, 5, 0);
    step(B, C, 4, 1);
    step(C, B, 3, 2);
    step(B, C, 2, 2);
    step(C, B, 1, 2);
    step(B, C, 0, 3);

    float* tmp = H; H = C; C = tmp;
  }
  float* freeA = A;
  float* freeB = B;
  float* freeC = C;

  // ---- deblock j=2 on mesh 1 via fused pool+MFMA Clenshaw (bf16) ----
  uint4* Ab1 = (uint4*)freeA;
  uint4* Bb1 = (uint4*)freeB;
  uint4* Cb1 = (uint4*)freeC;
  {
    int n = N[1];  // 10000
    dim3 gmf(n / 4);
    hipLaunchKernelGGL((pool_mfma_kernel<0>), gmf, dim3(256), 0, stream,
                       (const void*)H, offs_all + DP[1], cwc_arena,
                       Ab1, Bb1, Wt2 + (size_t)5 * 128, n);
    auto dstep = [&](const uint4* b1, uint4* b2o, int k, int mode) {
      cheb_mfma32_kernel<<<gmf, dim3(256), 0, stream>>>(
          Ab1, b1, b2o, Wt2 + (size_t)k * 128, b_[2],
          offs_all + DE[1], cwc_arena, n, mode);
    };
    dstep(Bb1, Cb1, 4, 1);
    dstep(Cb1, Bb1, 3, 2);
    dstep(Bb1, Cb1, 2, 2);
    dstep(Cb1, Bb1, 1, 2);
    dstep(Bb1, Cb1, 0, 3);   // h1 linear bf16 in Cb1
  }

  // ---- level 0: fused pool+MFMA Clenshaw + out conv ----
  {
    int n = N[0];
    int nr = n * 16;
    const int* offs_e = offs_all + DE[0];
    dim3 gmf(n / 4);

    hipLaunchKernelGGL((pool_mfma_kernel<1>), gmf, dim3(256), 0, stream,
                       (const void*)Cb1, offs_all + DP[0], cwc_arena,
                       Ab, Bb, Wt3 + (size_t)5 * 128, n);

    auto dstep = [&](const uint4* b1, uint4* b2o, int k, int mode) {
      cheb_mfma32_kernel<<<gmf, dim3(256), 0, stream>>>(
          Ab, b1, b2o, Wt3 + (size_t)k * 128, b_[3],
          offs_e, cwc_arena, n, mode);
    };
    dstep(Bb, Cb, 4, 1);
    dstep(Cb, Bb, 3, 2);
    dstep(Bb, Cb, 2, 2);
    dstep(Cb, Bb, 1, 2);
    dstep(Bb, Cb, 0, 3);   // h0 linear bf16 in Cb

    dim3 gr(cdiv(nr, TB));
    gemm_out_all_kernel<<<gr, dim3(TB), 0, stream>>>((const uint4*)Cb, W_[4], c_all, nr);
    float* dout = (float*)d_out;
    auto ostep = [&](const float* b1, float* b2o, int k, int mode) {
      cheb_out_step_kernel<<<gr, dim3(TB), 0, stream>>>(
          c_all, k, b1, b2o, b_[4], offs_e, cwc_arena, n, dout, mode);
    };
    ostep(nullptr, ob1, 5, 0);
    ostep(ob1, ob2, 4, 1);
    ostep(ob2, ob1, 3, 2);
    ostep(ob1, ob2, 2, 2);
    ostep(ob2, ob1, 1, 2);
    ostep(ob1, ob2, 0, 3);
  }
}